// Round 9
// baseline (179.338 us; speedup 1.0000x reference)
//
#include <hip/hip_runtime.h>

namespace {
constexpr int Bc  = 16;
constexpr int Nc  = 96;
constexpr int KRc = 16;
constexpr int KAc = 8;
constexpr int NOUT = KRc + KAc;        // 24
constexpr int NNb  = Nc - 1;           // 95 neighbors per atom
constexpr int PADN = 144;              // padded pair-shifted arrays (95+49)
constexpr float RCRf = 5.2f;
constexpr float RCAf = 3.5f;
constexpr float L2E  = 1.4426950408889634f;
}

typedef float v2f __attribute__((ext_vector_type(2)));
typedef float v4f __attribute__((ext_vector_type(4)));

__device__ __forceinline__ v2f sp(float x) { return (v2f){x, x}; }
__device__ __forceinline__ v2f pfma(v2f a, v2f b, v2f c) {
    return __builtin_elementwise_fma(a, b, c);
}
__device__ __forceinline__ v2f pmax(v2f a, v2f b) {
    return __builtin_elementwise_max(a, b);
}
__device__ __forceinline__ v2f pexp2(v2f x) {
    return (v2f){__builtin_amdgcn_exp2f(x.x), __builtin_amdgcn_exp2f(x.y)};
}
__device__ __forceinline__ v2f pcosr(v2f rev) {   // cos(2*pi*rev), rev >= 0
    return (v2f){__builtin_amdgcn_cosf(__builtin_amdgcn_fractf(rev.x)),
                 __builtin_amdgcn_cosf(__builtin_amdgcn_fractf(rev.y))};
}
__device__ __forceinline__ v2f psqrt(v2f x) {
    return (v2f){__builtin_amdgcn_sqrtf(x.x), __builtin_amdgcn_sqrtf(x.y)};
}
__device__ __forceinline__ float cos_rev(float rev) {
    return __builtin_amdgcn_cosf(__builtin_amdgcn_fractf(rev));
}

// MODE: 0 = full, 2 = staging+radial only, 3 = staging+angular only.
// REP: workload repeats (runtime); rep-dependence via opaque zero so the
// compiler cannot fold reps (rz = zero*rep is provably 0 only at rep==0,
// so REP=1 is bit-exact with the R8 kernel).
template<int MODE>
__device__ __forceinline__ void ani_body(
    const float* __restrict__ coords, const int* __restrict__ atom_types,
    const float* __restrict__ EtaR,  const float* __restrict__ ShfR,
    const float* __restrict__ Zeta,  const float* __restrict__ EtaA,
    float* __restrict__ dst, int REP)
{
    const int bi = blockIdx.x;             // b*N + i
    const int b  = bi / Nc;
    const int i  = bi - b * Nc;
    const int t  = threadIdx.x;

    __shared__ float4 su[NNb];             // unit vec x,y,z + d
    __shared__ float  ufa[NNb], sfr[NNb];
    __shared__ v4f  pxy[PADN];             // {x[s],x[s1],y[s],y[s1]}
    __shared__ v4f  pzd[PADN];             // {z[s],z[s1],d[s],d[s1]}
    __shared__ v2f  pfa[PADN];             // {fa[s],fa[s1]}
    __shared__ float pr[16][KRc];
    __shared__ float red[4][KAc];

    const int ti = atom_types[i];

    // ---- fast-path detection (uniform scalar loads, outside rep loop) ----
    bool fast;
    float ea0, dLs, c10;
    {
        float z0 = Zeta[ti * KAc + 0];
        bool zu = true;
#pragma unroll
        for (int k = 1; k < KAc; ++k) zu = zu && (Zeta[ti * KAc + k] == z0);
        float e0v = EtaA[ti * KAc + 0] * L2E;
        float e1v = EtaA[ti * KAc + 1] * L2E;
        float dv  = e1v - e0v;
        bool ar = true;
#pragma unroll
        for (int k = 2; k < KAc; ++k) {
            float ev = EtaA[ti * KAc + k] * L2E;
            ar = ar && (fabsf(ev - (e0v + dv * (float)k)) <=
                        1e-5f * fabsf(ev) + 1e-7f);
        }
        fast = zu && ar && (z0 == 32.0f);
        ea0 = e0v; dLs = dv; c10 = 1.0f - z0;
    }

    float zero;
    asm volatile("v_mov_b32 %0, 0" : "=v"(zero));
    float outa = 0.0f, outr = 0.0f;

    for (int rep = 0; rep < REP; ++rep) {
        const float rz = zero * (float)rep;     // 0, but opaque for rep>0
        __syncthreads();                        // protect LDS overwrite

        // ---- phase 1: scalar per-neighbor staging ----
        if (t < NNb) {
            const float* cb = coords + (size_t)(b * Nc) * 3;
            int j = t + (t >= i);
            float dx = cb[i*3+0] - cb[j*3+0] + rz;
            float dy = cb[i*3+1] - cb[j*3+1] + rz;
            float dz = cb[i*3+2] - cb[j*3+2] + rz;
            float d2 = dx*dx + dy*dy + dz*dz;
            float d  = __builtin_amdgcn_sqrtf(d2);
            float inv = __builtin_amdgcn_rcpf(d);
            su[t]  = make_float4(dx*inv, dy*inv, dz*inv, d);
            ufa[t] = fmaf(cos_rev(d * (0.5f / RCAf)), 0.5f, 0.5f);
            sfr[t] = fmaf(cos_rev(d * (0.5f / RCRf)), 0.5f, 0.5f);
        }
        __syncthreads();

        // ---- phase 2: pair-shifted packed SoA (angular operand) ----
        if constexpr (MODE != 2) {
            if (t < NNb) {
                int s1 = t + 1; if (s1 >= NNb) s1 = 0;
                float4 a = su[t], c = su[s1];
                pxy[t] = (v4f){a.x, c.x, a.y, c.y};
                pzd[t] = (v4f){a.z, c.z, a.w, c.w};
                pfa[t] = (v2f){ufa[t], ufa[s1]};
            }
            if (t < PADN - NNb) {              // mirror slots 0..48
                int s1 = t + 1;
                float4 a = su[t], c = su[s1];
                pxy[NNb + t] = (v4f){a.x, c.x, a.y, c.y};
                pzd[NNb + t] = (v4f){a.z, c.z, a.w, c.w};
                pfa[NNb + t] = (v2f){ufa[t], ufa[s1]};
            }
        }

        // ---- radial G2 ----
        if constexpr (MODE != 3) {
            const int k = t & 15, g2 = t >> 4;
            float er  = EtaR[ti * KRc + k];
            float sr  = ShfR[ti * KRc + k];
            float erL = -er * L2E;
            float acc = 0.0f;
            for (int jj = g2; jj < NNb; jj += 16) {
                float dd = su[jj].w - sr;
                acc += __builtin_amdgcn_exp2f(erL * dd * dd) * sfr[jj];
            }
            pr[g2][k] = acc;
        }
        __syncthreads();

        // ---- angular G3 ----
        if constexpr (MODE != 2) {
            const bool act = (t < 2 * NNb);
            const int  g   = (t >= NNb) ? 1 : 0;
            const int  j   = act ? (t - g * NNb) : 0;
            const float4 A  = su[j];
            const float faj = act ? ufa[j] : 0.0f;
            const float d2A  = A.w * A.w;
            const float m2Aw = -2.0f * A.w;
            const int   j2b  = j + (g ? 25 : 1);

            float av[KAc];

            if (fast) {
                v2f acc2[KAc];
#pragma unroll
                for (int k = 0; k < KAc; ++k) acc2[k] = sp(0.0f);

                if (act) {
                    const v2f fajv  = sp(faj);
                    const v2f lastm = g ? (v2f){faj, 0.0f} : fajv;

#define ANG_IT(IT, FAJV)                                                    \
                    {                                                       \
                        v4f xy = pxy[j2b + 2 * (IT)];                       \
                        v4f zd = pzd[j2b + 2 * (IT)];                       \
                        v2f fb = pfa[j2b + 2 * (IT)];                       \
                        v2f Bx = xy.xy, By = xy.zw;                         \
                        v2f Bz = zd.xy, Bw = zd.zw;                         \
                        v2f cosv = pfma(sp(A.x), Bx,                        \
                                        pfma(sp(A.y), By, sp(A.z)*Bz));     \
                        v2f sAB  = pfma(Bw, Bw, sp(d2A));                   \
                        v2f d23sq = pmax(pfma(sp(m2Aw)*Bw, cosv, sAB),      \
                                         sp(0.0f));                         \
                        v2f f23 = pfma(pcosr(psqrt(d23sq)*sp(0.5f/RCAf)),   \
                                       sp(0.5f), sp(0.5f));                 \
                        v2f fprod = (FAJV) * fb * f23;                      \
                        v2f s  = sAB + d23sq;                               \
                        v2f tt = pmax(sp(1.0f) + cosv, sp(0.0f));           \
                        v2f t2 = tt*tt, t4 = t2*t2, t8 = t4*t4, t16 = t8*t8;\
                        v2f F  = t16 * t16 * fprod;                         \
                        v2f e0 = pexp2(pfma(sp(-ea0), s, sp(c10)));         \
                        v2f q  = pexp2(sp(-dLs) * s);                       \
                        v2f q2 = q * q;                                     \
                        v2f e1 = e0*q,  e2 = e0*q2, e3 = e1*q2;             \
                        v2f e4 = e2*q2, e5 = e3*q2, e6 = e4*q2, e7 = e5*q2; \
                        acc2[0] = pfma(F, e0, acc2[0]);                     \
                        acc2[1] = pfma(F, e1, acc2[1]);                     \
                        acc2[2] = pfma(F, e2, acc2[2]);                     \
                        acc2[3] = pfma(F, e3, acc2[3]);                     \
                        acc2[4] = pfma(F, e4, acc2[4]);                     \
                        acc2[5] = pfma(F, e5, acc2[5]);                     \
                        acc2[6] = pfma(F, e6, acc2[6]);                     \
                        acc2[7] = pfma(F, e7, acc2[7]);                     \
                    }

                    ANG_IT(0, fajv)  ANG_IT(1, fajv)  ANG_IT(2, fajv)
                    ANG_IT(3, fajv)  ANG_IT(4, fajv)  ANG_IT(5, fajv)
                    ANG_IT(6, fajv)  ANG_IT(7, fajv)  ANG_IT(8, fajv)
                    ANG_IT(9, fajv)  ANG_IT(10, fajv) ANG_IT(11, lastm)
#undef ANG_IT
                }
#pragma unroll
                for (int k = 0; k < KAc; ++k) av[k] = acc2[k].x + acc2[k].y;
            } else {
                float zek[KAc], c1k[KAc], eaL[KAc];
#pragma unroll
                for (int k = 0; k < KAc; ++k) {
                    float z = Zeta[ti * KAc + k];
                    zek[k] = z;
                    c1k[k] = 1.0f - z;
                    eaL[k] = EtaA[ti * KAc + k] * L2E;
                }
                float accS[KAc];
#pragma unroll
                for (int k = 0; k < KAc; ++k) accS[k] = 0.0f;
                if (act) {
                    for (int r = 0; r < 24; ++r) {
                        int rr = (g ? 25 : 1) + r;
                        float lv = (rr <= 47) ? 1.0f : 0.0f;
                        int j2 = j + rr; if (j2 >= NNb) j2 -= NNb;
                        float4 Bq = su[j2];
                        float fb = ufa[j2];
                        float cosv = fmaf(A.x, Bq.x, fmaf(A.y, Bq.y, A.z*Bq.z));
                        float sAB  = fmaf(Bq.w, Bq.w, d2A);
                        float d23sq = fmaxf(fmaf(m2Aw*Bq.w, cosv, sAB), 0.0f);
                        float d23 = __builtin_amdgcn_sqrtf(d23sq);
                        float f23 = fmaf(cos_rev(d23*(0.5f/RCAf)), 0.5f, 0.5f);
                        float fprod = faj * fb * f23 * lv;
                        float s  = sAB + d23sq;
                        float tt = fmaxf(1.0f + cosv, 0.0f);
                        float l2 = __builtin_amdgcn_logf(tt);
#pragma unroll
                        for (int k = 0; k < KAc; ++k) {
                            float E = fmaf(zek[k], l2, c1k[k]);
                            E = fmaf(-eaL[k], s, E);
                            accS[k] += __builtin_amdgcn_exp2f(E) * fprod;
                        }
                    }
                }
#pragma unroll
                for (int k = 0; k < KAc; ++k) av[k] = accS[k];
            }

            // wave + block reduction
            const int lane = t & 63, wv = t >> 6;
#pragma unroll
            for (int k = 0; k < KAc; ++k) {
                float v = av[k];
#pragma unroll
                for (int off = 32; off; off >>= 1) v += __shfl_xor(v, off, 64);
                if (lane == 0) red[wv][k] = v;
            }
            __syncthreads();
            if (t < KAc)
                outa += red[0][t] + red[1][t] + red[2][t] + red[3][t];
        }

        if constexpr (MODE != 3) {
            if (t < KRc) {
                float s = 0.0f;
#pragma unroll
                for (int g2 = 0; g2 < 16; ++g2) s += pr[g2][t];
                outr += s;
            }
        }
    }

    if constexpr (MODE != 2) {
        if (t < KAc) dst[bi * NOUT + KRc + t] = outa;
    }
    if constexpr (MODE != 3) {
        if (t < KRc) dst[bi * NOUT + t] = outr;
    }
}

__global__ __launch_bounds__(256, 6) void ani_feat_kernel(
    const float* __restrict__ c, const int* __restrict__ at,
    const float* __restrict__ er, const float* __restrict__ sr,
    const float* __restrict__ ze, const float* __restrict__ ea,
    float* __restrict__ out)
{ ani_body<0>(c, at, er, sr, ze, ea, out, 1); }

__global__ __launch_bounds__(256, 6) void diagA_full_x4(
    const float* __restrict__ c, const int* __restrict__ at,
    const float* __restrict__ er, const float* __restrict__ sr,
    const float* __restrict__ ze, const float* __restrict__ ea,
    float* __restrict__ dst)
{ ani_body<0>(c, at, er, sr, ze, ea, dst, 4); }

__global__ __launch_bounds__(256, 6) void diagB_stage_rad_x24(
    const float* __restrict__ c, const int* __restrict__ at,
    const float* __restrict__ er, const float* __restrict__ sr,
    const float* __restrict__ ze, const float* __restrict__ ea,
    float* __restrict__ dst)
{ ani_body<2>(c, at, er, sr, ze, ea, dst, 24); }

__global__ __launch_bounds__(256, 6) void diagC_stage_ang_x5(
    const float* __restrict__ c, const int* __restrict__ at,
    const float* __restrict__ er, const float* __restrict__ sr,
    const float* __restrict__ ze, const float* __restrict__ ea,
    float* __restrict__ dst)
{ ani_body<3>(c, at, er, sr, ze, ea, dst, 5); }

__global__ __launch_bounds__(256) void diagD_full_nobound_x4(
    const float* __restrict__ c, const int* __restrict__ at,
    const float* __restrict__ er, const float* __restrict__ sr,
    const float* __restrict__ ze, const float* __restrict__ ea,
    float* __restrict__ dst)
{ ani_body<0>(c, at, er, sr, ze, ea, dst, 4); }

extern "C" void kernel_launch(void* const* d_in, const int* in_sizes, int n_in,
                              void* d_out, int out_size, void* d_ws, size_t ws_size,
                              hipStream_t stream) {
    const float* coords     = (const float*)d_in[0];
    const int*   atom_types = (const int*)d_in[1];
    const float* EtaR       = (const float*)d_in[2];
    const float* ShfR       = (const float*)d_in[3];
    const float* Zeta       = (const float*)d_in[4];
    const float* EtaA       = (const float*)d_in[5];
    float* out = (float*)d_out;

    dim3 grid(Bc * Nc), block(256);

    // real output (bit-exact with R8)
    ani_feat_kernel<<<grid, block, 0, stream>>>(coords, atom_types, EtaR,
                                                ShfR, Zeta, EtaA, out);

    // diagnostic dispatches (write only to d_ws scratch regions)
    const size_t need = 4u * 40960u * sizeof(float);
    if (ws_size >= need) {
        float* wsf = (float*)d_ws;
        diagA_full_x4<<<grid, block, 0, stream>>>(coords, atom_types, EtaR,
                                                  ShfR, Zeta, EtaA, wsf);
        diagB_stage_rad_x24<<<grid, block, 0, stream>>>(coords, atom_types,
                                                        EtaR, ShfR, Zeta, EtaA,
                                                        wsf + 40960);
        diagC_stage_ang_x5<<<grid, block, 0, stream>>>(coords, atom_types,
                                                       EtaR, ShfR, Zeta, EtaA,
                                                       wsf + 2 * 40960);
        diagD_full_nobound_x4<<<grid, block, 0, stream>>>(coords, atom_types,
                                                          EtaR, ShfR, Zeta,
                                                          EtaA,
                                                          wsf + 3 * 40960);
    }
}

// Round 10
// 29.982 us; speedup vs baseline: 5.9815x; 5.9815x over previous
//
#include <hip/hip_runtime.h>

namespace {
constexpr int Bc  = 16;
constexpr int Nc  = 96;
constexpr int KRc = 16;
constexpr int KAc = 8;
constexpr int NOUT = KRc + KAc;        // 24
constexpr int NNb  = Nc - 1;           // 95 neighbors per atom
constexpr int TABN = Nc * Nc;          // 9216 table entries per batch
constexpr float RCRf = 5.2f;
constexpr float RCAf = 3.5f;
constexpr float L2E  = 1.4426950408889634f;
}

__device__ __forceinline__ float cos_rev(float rev) {   // cos(2*pi*rev)
    return __builtin_amdgcn_cosf(__builtin_amdgcn_fractf(rev));
}
__device__ __forceinline__ float exp2g(float x) {
    return __builtin_amdgcn_exp2f(x);
}

// ---- Kernel A: per-batch pair tables, delta layout ----
// tab[b*TABN + dlt*96 + a] = {f23(d)*exp2(-ea0*d2), exp2(-dLs*d2)} for the
// atom pair (a, (a+dlt)%96) of batch b. Params from atom_types[0]'s row
// (kernel B verifies its own params match before using the table).
__global__ __launch_bounds__(256) void build_tab_kernel(
    const float* __restrict__ coords, const int* __restrict__ atom_types,
    const float* __restrict__ EtaA, float2* __restrict__ tab)
{
    const int blk = blockIdx.x;            // 64 = 16 batches x 4 quarters
    const int b = blk >> 2, qt = blk & 3;
    const int t = threadIdx.x;
    __shared__ float cx[Nc], cy[Nc], cz[Nc];
    if (t < Nc) {
        const float* cb = coords + (size_t)b * Nc * 3;
        cx[t] = cb[t*3+0]; cy[t] = cb[t*3+1]; cz[t] = cb[t*3+2];
    }
    const int t0 = atom_types[0];
    const float ea0 = EtaA[t0*KAc] * L2E;
    const float dLs = EtaA[t0*KAc+1] * L2E - ea0;
    __syncthreads();
#pragma unroll
    for (int r = 0; r < 9; ++r) {          // 4*9*256 = 9216
        int e = qt * 2304 + r * 256 + t;
        int dlt = e / 96;
        int a = e - dlt * 96;
        int c = a + dlt; if (c >= Nc) c -= Nc;
        float dx = cx[a]-cx[c], dy = cy[a]-cy[c], dz = cz[a]-cz[c];
        float d2 = dx*dx + dy*dy + dz*dz;
        float d  = __builtin_amdgcn_sqrtf(d2);
        float f  = fmaf(cos_rev(d * (0.5f/RCAf)), 0.5f, 0.5f);
        tab[(size_t)b*TABN + e] = make_float2(f * exp2g(-ea0*d2),
                                              exp2g(-dLs*d2));
    }
}

// ---- Kernel B ----
// 256 thr/block, grid 1536 (6 blocks/CU). Angular: t<190 active, j = t%95
// fixed per thread (A in regs), g = t/95 picks rr half (g=0: rr 1..24,
// g=1: rr 25..48, rr==48 masked). Pairs (j,(j+rr)%95) cover C(95,2) once.
// Fast path: term_k = tt^32 * 2^(1-32) * [FEa*FEb*P1] * [Qa*Qb*P2]^k
// with FE/Q staged per neighbor and P1/P2 gathered from the batch table
// (USETAB) or computed inline (!USETAB). Zero trans ops in USETAB loop.
template<bool USETAB>
__global__ __launch_bounds__(256, 6) void ani_feat_tab_kernel(
    const float* __restrict__ coords,      // (B,N,3)
    const int*   __restrict__ atom_types,  // (N,)
    const float* __restrict__ EtaR,        // (T,KR)
    const float* __restrict__ ShfR,        // (T,KR)
    const float* __restrict__ Zeta,        // (T,KA)
    const float* __restrict__ EtaA,        // (T,KA)
    const float2* __restrict__ tab,
    float* __restrict__ out)               // (B,N,24)
{
    const int bi = blockIdx.x;             // b*N + i
    const int b  = bi / Nc;
    const int i  = bi - b * Nc;
    const int t  = threadIdx.x;

    __shared__ float4 su4[NNb];            // ux,uy,uz, FE = fa*exp2(-ea0*d2)
    __shared__ float  sQ[NNb];             // exp2(-dLs*d2)
    __shared__ float  sd[NNb];             // d
    __shared__ float  sfa[NNb];            // fa (generic path)
    __shared__ float  sfr[NNb];            // radial cutoff
    __shared__ float  pr[16][KRc];
    __shared__ float  red[4][KAc];

    const int ti = atom_types[i];

    // ---- fast-path detection (uniform scalar loads) ----
    bool fast;
    float ea0, dLs, c10;
    {
        float z0 = Zeta[ti * KAc + 0];
        bool zu = true;
#pragma unroll
        for (int k = 1; k < KAc; ++k) zu = zu && (Zeta[ti * KAc + k] == z0);
        ea0 = EtaA[ti * KAc + 0] * L2E;
        float e1v = EtaA[ti * KAc + 1] * L2E;
        dLs = e1v - ea0;
        bool ar = true;
#pragma unroll
        for (int k = 2; k < KAc; ++k) {
            float ev = EtaA[ti * KAc + k] * L2E;
            ar = ar && (fabsf(ev - (ea0 + dLs * (float)k)) <=
                        1e-5f * fabsf(ev) + 1e-7f);
        }
        fast = zu && ar && (z0 == 32.0f);
        if (USETAB) {   // table baked with type0 params; must match exactly
            int t0a = atom_types[0];
            float ea00 = EtaA[t0a * KAc + 0] * L2E;
            float dL00 = EtaA[t0a * KAc + 1] * L2E - ea00;
            fast = fast && (ea0 == ea00) && (dLs == dL00);
        }
        c10 = 1.0f - z0;
    }

    // ---- staging ----
    if (t < NNb) {
        const float* cb = coords + (size_t)(b * Nc) * 3;
        int jg = t + (t >= i);
        float dx = cb[i*3+0] - cb[jg*3+0];
        float dy = cb[i*3+1] - cb[jg*3+1];
        float dz = cb[i*3+2] - cb[jg*3+2];
        float d2 = dx*dx + dy*dy + dz*dz;
        float d  = __builtin_amdgcn_sqrtf(d2);
        float inv = __builtin_amdgcn_rcpf(d);
        float fa = fmaf(cos_rev(d * (0.5f / RCAf)), 0.5f, 0.5f);
        su4[t] = make_float4(dx*inv, dy*inv, dz*inv, fa * exp2g(-ea0 * d2));
        sQ[t]  = exp2g(-dLs * d2);
        sd[t]  = d;
        sfa[t] = fa;
        sfr[t] = fmaf(cos_rev(d * (0.5f / RCRf)), 0.5f, 0.5f);
    }
    __syncthreads();

    // ---- radial G2 ----
    {
        const int k = t & 15, g2 = t >> 4;
        float er  = EtaR[ti * KRc + k];
        float sr  = ShfR[ti * KRc + k];
        float erL = -er * L2E;
        float acc = 0.0f;
        for (int jj = g2; jj < NNb; jj += 16) {
            float dd = sd[jj] - sr;
            acc += exp2g(erL * dd * dd) * sfr[jj];
        }
        pr[g2][k] = acc;
    }

    // ---- angular G3 ----
    const bool act = (t < 2 * NNb);        // 190 active
    const int  g   = (t >= NNb) ? 1 : 0;
    const int  j   = act ? (t - g * NNb) : 0;
    const float4 A  = su4[j];
    const float Qa  = sQ[j];
    const float p21z = exp2g(c10);         // 2^(1-zeta)
    const float FEa2 = act ? A.w * p21z : 0.0f;
    const float lastf = g ? 0.0f : 1.0f;   // mask rr==48 (iter r==23, g==1)
    const int  jg1 = j + (j >= i);
    const int  rr0 = g ? 25 : 1;
    int nj2 = j + rr0; if (nj2 >= NNb) nj2 -= NNb;
    const float2* tb = tab + (size_t)b * TABN;

    float av[KAc];

    if (fast) {
        float acc[KAc];
#pragma unroll
        for (int k = 0; k < KAc; ++k) acc[k] = 0.0f;
        const float dA  = sd[j];
        const float m2A = -2.0f * dA;
        const float d2A = dA * dA;

#pragma unroll 4
        for (int r = 0; r < 24; ++r) {
            float4 Bv = su4[nj2];
            float Qb  = sQ[nj2];
            float cosv = fmaf(A.x, Bv.x, fmaf(A.y, Bv.y, A.z * Bv.z));
            float P1, P2;
            if constexpr (USETAB) {
                int jg2 = nj2 + (nj2 >= i);
                int dlt = jg2 - jg1; dlt += (dlt >> 31) & 96;
                float2 P = tb[dlt * 96 + jg1];
                P1 = P.x; P2 = P.y;
            } else {
                float d13 = sd[nj2];
                float sAB = fmaf(d13, d13, d2A);
                float d23sq = fmaxf(fmaf(m2A * d13, cosv, sAB), 0.0f);
                float f23 = fmaf(cos_rev(__builtin_amdgcn_sqrtf(d23sq) *
                                         (0.5f / RCAf)), 0.5f, 0.5f);
                P1 = f23 * exp2g(-ea0 * d23sq);
                P2 = exp2g(-dLs * d23sq);
            }
            float tt = fmaxf(1.0f + cosv, 0.0f);
            float t2 = tt*tt, t4 = t2*t2, t8 = t4*t4, t16 = t8*t8;
            float t32 = t16 * t16;
            float m = (r == 23) ? lastf : 1.0f;
            float F = t32 * (FEa2 * m) * (Bv.w * P1);
            float q = (Qa * Qb) * P2;
            float q2 = q * q;
            acc[0] += F;
            float u1 = F * q;   acc[1] += u1;
            float u2 = F * q2;  acc[2] += u2;
            float u3 = u1 * q2; acc[3] += u3;
            float u4 = u2 * q2; acc[4] += u4;
            float u5 = u3 * q2; acc[5] += u5;
            float u6 = u4 * q2; acc[6] += u6;
            float u7 = u5 * q2; acc[7] += u7;
            ++nj2; if (nj2 >= NNb) nj2 = 0;
        }
#pragma unroll
        for (int k = 0; k < KAc; ++k) av[k] = acc[k];
    } else {
        // generic: arbitrary Zeta/EtaA, everything in-loop
        float zek[KAc], c1k[KAc], eaL[KAc];
#pragma unroll
        for (int k = 0; k < KAc; ++k) {
            float z = Zeta[ti * KAc + k];
            zek[k] = z;
            c1k[k] = 1.0f - z;
            eaL[k] = EtaA[ti * KAc + k] * L2E;
        }
        float accS[KAc];
#pragma unroll
        for (int k = 0; k < KAc; ++k) accS[k] = 0.0f;
        const float dA  = sd[j];
        const float m2A = -2.0f * dA;
        const float d2A = dA * dA;
        const float faj = act ? sfa[j] : 0.0f;

        for (int r = 0; r < 24; ++r) {
            float4 Bv = su4[nj2];
            float d13 = sd[nj2];
            float fb  = sfa[nj2];
            float cosv = fmaf(A.x, Bv.x, fmaf(A.y, Bv.y, A.z * Bv.z));
            float sAB = fmaf(d13, d13, d2A);
            float d23sq = fmaxf(fmaf(m2A * d13, cosv, sAB), 0.0f);
            float f23 = fmaf(cos_rev(__builtin_amdgcn_sqrtf(d23sq) *
                                     (0.5f / RCAf)), 0.5f, 0.5f);
            float m = (r == 23) ? lastf : 1.0f;
            float fprod = faj * fb * f23 * m;
            float s  = sAB + d23sq;
            float tt = fmaxf(1.0f + cosv, 0.0f);
            float l2 = __builtin_amdgcn_logf(tt);   // log2; -inf at 0 ok
#pragma unroll
            for (int k = 0; k < KAc; ++k) {
                float E = fmaf(zek[k], l2, c1k[k]);
                E = fmaf(-eaL[k], s, E);
                accS[k] += exp2g(E) * fprod;
            }
            ++nj2; if (nj2 >= NNb) nj2 = 0;
        }
#pragma unroll
        for (int k = 0; k < KAc; ++k) av[k] = accS[k];
    }

    // ---- reductions ----
    const int lane = t & 63, wv = t >> 6;
#pragma unroll
    for (int k = 0; k < KAc; ++k) {
        float v = av[k];
#pragma unroll
        for (int off = 32; off; off >>= 1) v += __shfl_xor(v, off, 64);
        if (lane == 0) red[wv][k] = v;
    }
    __syncthreads();

    if (t < KAc) {
        out[bi * NOUT + KRc + t] =
            red[0][t] + red[1][t] + red[2][t] + red[3][t];
    }
    if (t < KRc) {
        float s = 0.0f;
#pragma unroll
        for (int g2 = 0; g2 < 16; ++g2) s += pr[g2][t];
        out[bi * NOUT + t] = s;
    }
}

extern "C" void kernel_launch(void* const* d_in, const int* in_sizes, int n_in,
                              void* d_out, int out_size, void* d_ws, size_t ws_size,
                              hipStream_t stream) {
    const float* coords     = (const float*)d_in[0];
    const int*   atom_types = (const int*)d_in[1];
    const float* EtaR       = (const float*)d_in[2];
    const float* ShfR       = (const float*)d_in[3];
    const float* Zeta       = (const float*)d_in[4];
    const float* EtaA       = (const float*)d_in[5];
    float* out = (float*)d_out;

    dim3 grid(Bc * Nc), block(256);
    const size_t need = (size_t)Bc * TABN * sizeof(float2);   // 1.18 MB

    if (ws_size >= need) {
        float2* tab = (float2*)d_ws;
        build_tab_kernel<<<dim3(64), block, 0, stream>>>(coords, atom_types,
                                                         EtaA, tab);
        ani_feat_tab_kernel<true><<<grid, block, 0, stream>>>(
            coords, atom_types, EtaR, ShfR, Zeta, EtaA, tab, out);
    } else {
        ani_feat_tab_kernel<false><<<grid, block, 0, stream>>>(
            coords, atom_types, EtaR, ShfR, Zeta, EtaA, nullptr, out);
    }
}

// Round 11
// 23.851 us; speedup vs baseline: 7.5190x; 1.2570x over previous
//
#include <hip/hip_runtime.h>

namespace {
constexpr int Bc  = 16;
constexpr int Nc  = 96;
constexpr int KRc = 16;
constexpr int KAc = 8;
constexpr int NOUT = KRc + KAc;        // 24
constexpr int NNb  = Nc - 1;           // 95 neighbors per atom
constexpr int PADN = 144;              // padded pair-shifted arrays (95+49)
constexpr int NFULL = 1024;            // atoms with a single block
constexpr float RCRf = 5.2f;
constexpr float RCAf = 3.5f;
constexpr float L2E  = 1.4426950408889634f;
}

typedef float v2f __attribute__((ext_vector_type(2)));
typedef float v4f __attribute__((ext_vector_type(4)));

__device__ __forceinline__ v2f sp(float x) { return (v2f){x, x}; }
__device__ __forceinline__ v2f pfma(v2f a, v2f b, v2f c) {
    return __builtin_elementwise_fma(a, b, c);
}
__device__ __forceinline__ v2f pmax(v2f a, v2f b) {
    return __builtin_elementwise_max(a, b);
}
__device__ __forceinline__ v2f pexp2(v2f x) {
    return (v2f){__builtin_amdgcn_exp2f(x.x), __builtin_amdgcn_exp2f(x.y)};
}
__device__ __forceinline__ v2f pcosr(v2f rev) {   // cos(2*pi*rev), rev >= 0
    return (v2f){__builtin_amdgcn_cosf(__builtin_amdgcn_fractf(rev.x)),
                 __builtin_amdgcn_cosf(__builtin_amdgcn_fractf(rev.y))};
}
__device__ __forceinline__ v2f psqrt(v2f x) {
    return (v2f){__builtin_amdgcn_sqrtf(x.x), __builtin_amdgcn_sqrtf(x.y)};
}
__device__ __forceinline__ float cos_rev(float rev) {
    return __builtin_amdgcn_cosf(__builtin_amdgcn_fractf(rev));
}

// R8 structure + full-occupancy split:
// grid 2048 x 256 thr = exactly 8 blocks/CU (VGPR cap 64; measured need 40).
// Blocks 0..1023: atom = blk, packed iters 0..11.
// Blocks 1024..2047: atom = 1024 + (blk-1024)/2, half = (blk-1024)&1,
//   iters [6*half, 6*half+6). Angular partials combined via atomicAdd into
//   memset-zeroed out; radial stored by the primary block only.
__global__ __launch_bounds__(256, 8) void ani_feat_kernel(
    const float* __restrict__ coords,      // (B,N,3)
    const int*   __restrict__ atom_types,  // (N,)
    const float* __restrict__ EtaR,        // (T,KR)
    const float* __restrict__ ShfR,        // (T,KR)
    const float* __restrict__ Zeta,        // (T,KA)
    const float* __restrict__ EtaA,        // (T,KA)
    float* __restrict__ out)               // (B,N,24), pre-zeroed
{
    const int blk = blockIdx.x;
    const bool split = (blk >= NFULL);
    const int  gma   = split ? (blk - NFULL) : 0;
    const int  bi    = split ? (NFULL + (gma >> 1)) : blk;   // b*N + i
    const int  half  = split ? (gma & 1) : 0;
    const bool primary = !split || (half == 0);
    const int b  = bi / Nc;
    const int i  = bi - b * Nc;
    const int t  = threadIdx.x;

    __shared__ float4 su[NNb];             // unit vec x,y,z + d
    __shared__ float  ufa[NNb], sfr[NNb];
    __shared__ v4f  pxy[PADN];             // {x[s],x[s1],y[s],y[s1]}
    __shared__ v4f  pzd[PADN];             // {z[s],z[s1],d[s],d[s1]}
    __shared__ v2f  pfa[PADN];             // {fa[s],fa[s1]}
    __shared__ float pr[16][KRc];
    __shared__ float red[4][KAc];

    const int ti = atom_types[i];

    // ---- phase 1: scalar per-neighbor staging ----
    if (t < NNb) {
        const float* cb = coords + (size_t)(b * Nc) * 3;
        int j = t + (t >= i);
        float dx = cb[i*3+0] - cb[j*3+0];
        float dy = cb[i*3+1] - cb[j*3+1];
        float dz = cb[i*3+2] - cb[j*3+2];
        float d2 = dx*dx + dy*dy + dz*dz;
        float d  = __builtin_amdgcn_sqrtf(d2);
        float inv = __builtin_amdgcn_rcpf(d);
        su[t]  = make_float4(dx*inv, dy*inv, dz*inv, d);
        ufa[t] = fmaf(cos_rev(d * (0.5f / RCAf)), 0.5f, 0.5f);
        sfr[t] = fmaf(cos_rev(d * (0.5f / RCRf)), 0.5f, 0.5f);
    }

    // ---- fast-path detection from scalar (uniform) loads only ----
    bool fast;
    float ea0, dLs, c10;
    {
        float z0 = Zeta[ti * KAc + 0];
        bool zu = true;
#pragma unroll
        for (int k = 1; k < KAc; ++k) zu = zu && (Zeta[ti * KAc + k] == z0);
        float e0v = EtaA[ti * KAc + 0] * L2E;
        float e1v = EtaA[ti * KAc + 1] * L2E;
        float dv  = e1v - e0v;
        bool ar = true;
#pragma unroll
        for (int k = 2; k < KAc; ++k) {
            float ev = EtaA[ti * KAc + k] * L2E;
            ar = ar && (fabsf(ev - (e0v + dv * (float)k)) <=
                        1e-5f * fabsf(ev) + 1e-7f);
        }
        fast = zu && ar && (z0 == 32.0f);
        ea0 = e0v; dLs = dv; c10 = 1.0f - z0;
    }

    __syncthreads();

    // ---- phase 2: pair-shifted packed SoA, padded (no wrap in walk) ----
    if (t < NNb) {
        int s1 = t + 1; if (s1 >= NNb) s1 = 0;
        float4 a = su[t], c = su[s1];
        pxy[t] = (v4f){a.x, c.x, a.y, c.y};
        pzd[t] = (v4f){a.z, c.z, a.w, c.w};
        pfa[t] = (v2f){ufa[t], ufa[s1]};
    }
    if (t < PADN - NNb) {                  // mirror slots 0..48 -> 95..143
        int s1 = t + 1;                    // t<=48 -> s1<=49, no wrap
        float4 a = su[t], c = su[s1];
        pxy[NNb + t] = (v4f){a.x, c.x, a.y, c.y};
        pzd[NNb + t] = (v4f){a.z, c.z, a.w, c.w};
        pfa[NNb + t] = (v2f){ufa[t], ufa[s1]};
    }

    // ---- radial G2 (primary block only) ----
    if (primary) {
        const int k = t & 15, g2 = t >> 4;
        float er  = EtaR[ti * KRc + k];
        float sr  = ShfR[ti * KRc + k];
        float erL = -er * L2E;
        float acc = 0.0f;
        for (int jj = g2; jj < NNb; jj += 16) {
            float dd = su[jj].w - sr;
            acc += __builtin_amdgcn_exp2f(erL * dd * dd) * sfr[jj];
        }
        pr[g2][k] = acc;
    }
    __syncthreads();

    // ---- angular G3 ----
    const bool act = (t < 2 * NNb);        // 190 active
    const int  g   = (t >= NNb) ? 1 : 0;
    const int  j   = act ? (t - g * NNb) : 0;
    const float4 A  = su[j];
    const float faj = act ? ufa[j] : 0.0f;
    const float d2A  = A.w * A.w;
    const float m2Aw = -2.0f * A.w;
    const int   itbase = split ? 6 * half : 0;
    const int   j2b  = j + (g ? 25 : 1) + 2 * itbase;   // padded-array base

    float av[KAc];

    if (fast) {
        v2f acc2[KAc];
#pragma unroll
        for (int k = 0; k < KAc; ++k) acc2[k] = sp(0.0f);

        if (act) {
            const v2f fajv  = sp(faj);
            // mask for global iter 11 (rr==48 y-lane dead when g==1)
            const v2f tailm = g ? (v2f){faj, 0.0f} : fajv;

#define ANG_IT(IT, FAJV)                                                    \
            {                                                               \
                v4f xy = pxy[j2b + 2 * (IT)];                               \
                v4f zd = pzd[j2b + 2 * (IT)];                               \
                v2f fb = pfa[j2b + 2 * (IT)];                               \
                v2f Bx = xy.xy, By = xy.zw;                                 \
                v2f Bz = zd.xy, Bw = zd.zw;                                 \
                v2f cosv = pfma(sp(A.x), Bx, pfma(sp(A.y), By, sp(A.z)*Bz));\
                v2f sAB  = pfma(Bw, Bw, sp(d2A));                           \
                v2f d23sq = pmax(pfma(sp(m2Aw)*Bw, cosv, sAB), sp(0.0f));   \
                v2f f23 = pfma(pcosr(psqrt(d23sq) * sp(0.5f/RCAf)),         \
                               sp(0.5f), sp(0.5f));                         \
                v2f fprod = (FAJV) * fb * f23;                              \
                v2f s  = sAB + d23sq;                                       \
                v2f tt = pmax(sp(1.0f) + cosv, sp(0.0f));                   \
                v2f t2 = tt*tt, t4 = t2*t2, t8 = t4*t4, t16 = t8*t8;        \
                v2f F  = t16 * t16 * fprod;                                 \
                v2f e0 = pexp2(pfma(sp(-ea0), s, sp(c10)));                 \
                v2f q  = pexp2(sp(-dLs) * s);                               \
                v2f q2 = q * q;                                             \
                v2f e1 = e0*q,  e2 = e0*q2, e3 = e1*q2;                     \
                v2f e4 = e2*q2, e5 = e3*q2, e6 = e4*q2, e7 = e5*q2;         \
                acc2[0] = pfma(F, e0, acc2[0]);                             \
                acc2[1] = pfma(F, e1, acc2[1]);                             \
                acc2[2] = pfma(F, e2, acc2[2]);                             \
                acc2[3] = pfma(F, e3, acc2[3]);                             \
                acc2[4] = pfma(F, e4, acc2[4]);                             \
                acc2[5] = pfma(F, e5, acc2[5]);                             \
                acc2[6] = pfma(F, e6, acc2[6]);                             \
                acc2[7] = pfma(F, e7, acc2[7]);                             \
            }

            if (!split) {
                ANG_IT(0, fajv)  ANG_IT(1, fajv)  ANG_IT(2, fajv)
                ANG_IT(3, fajv)  ANG_IT(4, fajv)  ANG_IT(5, fajv)
                ANG_IT(6, fajv)  ANG_IT(7, fajv)  ANG_IT(8, fajv)
                ANG_IT(9, fajv)  ANG_IT(10, fajv) ANG_IT(11, tailm)
            } else {
                const v2f last6 = half ? tailm : fajv;  // global iter 11
                ANG_IT(0, fajv)  ANG_IT(1, fajv)  ANG_IT(2, fajv)
                ANG_IT(3, fajv)  ANG_IT(4, fajv)  ANG_IT(5, last6)
            }
#undef ANG_IT
        }
#pragma unroll
        for (int k = 0; k < KAc; ++k) av[k] = acc2[k].x + acc2[k].y;
    } else {
        // generic fallback: reload params here (keeps fast path lean)
        float zek[KAc], c1k[KAc], eaL[KAc];
#pragma unroll
        for (int k = 0; k < KAc; ++k) {
            float z = Zeta[ti * KAc + k];
            zek[k] = z;
            c1k[k] = 1.0f - z;
            eaL[k] = EtaA[ti * KAc + k] * L2E;
        }
        float accS[KAc];
#pragma unroll
        for (int k = 0; k < KAc; ++k) accS[k] = 0.0f;

        if (act) {
            const int nr = split ? 12 : 24;       // scalar pairs this block
            int j2 = j + (g ? 25 : 1) + 2 * itbase;
            while (j2 >= NNb) j2 -= NNb;
            for (int r = 0; r < nr; ++r) {
                int rg = 2 * itbase + r;          // global pair index 0..23
                int rr = (g ? 25 : 1) + rg;
                float lv = (rr <= 47) ? 1.0f : 0.0f;
                float4 Bq = su[j2];
                float fb = ufa[j2];
                float cosv = fmaf(A.x, Bq.x, fmaf(A.y, Bq.y, A.z * Bq.z));
                float sAB  = fmaf(Bq.w, Bq.w, d2A);
                float d23sq = fmaxf(fmaf(m2Aw * Bq.w, cosv, sAB), 0.0f);
                float d23 = __builtin_amdgcn_sqrtf(d23sq);
                float f23 = fmaf(cos_rev(d23 * (0.5f / RCAf)), 0.5f, 0.5f);
                float fprod = faj * fb * f23 * lv;
                float s  = sAB + d23sq;
                float tt = fmaxf(1.0f + cosv, 0.0f);
                float l2 = __builtin_amdgcn_logf(tt);   // log2; -inf at 0 ok
#pragma unroll
                for (int k = 0; k < KAc; ++k) {
                    float E = fmaf(zek[k], l2, c1k[k]);
                    E = fmaf(-eaL[k], s, E);
                    accS[k] += __builtin_amdgcn_exp2f(E) * fprod;
                }
                ++j2; if (j2 >= NNb) j2 = 0;
            }
        }
#pragma unroll
        for (int k = 0; k < KAc; ++k) av[k] = accS[k];
    }

    // ---- reductions ----
    const int lane = t & 63, wv = t >> 6;
#pragma unroll
    for (int k = 0; k < KAc; ++k) {
        float v = av[k];
#pragma unroll
        for (int off = 32; off; off >>= 1) v += __shfl_xor(v, off, 64);
        if (lane == 0) red[wv][k] = v;
    }
    __syncthreads();

    if (t < KAc) {
        float v = red[0][t] + red[1][t] + red[2][t] + red[3][t];
        atomicAdd(&out[bi * NOUT + KRc + t], v);   // <=2 writers per atom
    }
    if (primary && t < KRc) {
        float s = 0.0f;
#pragma unroll
        for (int g2 = 0; g2 < 16; ++g2) s += pr[g2][t];
        out[bi * NOUT + t] = s;                    // single writer
    }
}

extern "C" void kernel_launch(void* const* d_in, const int* in_sizes, int n_in,
                              void* d_out, int out_size, void* d_ws, size_t ws_size,
                              hipStream_t stream) {
    const float* coords     = (const float*)d_in[0];
    const int*   atom_types = (const int*)d_in[1];
    const float* EtaR       = (const float*)d_in[2];
    const float* ShfR       = (const float*)d_in[3];
    const float* Zeta       = (const float*)d_in[4];
    const float* EtaA       = (const float*)d_in[5];
    float* out = (float*)d_out;

    hipMemsetAsync(out, 0, (size_t)out_size * sizeof(float), stream);
    ani_feat_kernel<<<dim3(2048), dim3(256), 0, stream>>>(
        coords, atom_types, EtaR, ShfR, Zeta, EtaA, out);
}

// Round 12
// 16.801 us; speedup vs baseline: 10.6741x; 1.4196x over previous
//
#include <hip/hip_runtime.h>

namespace {
constexpr int Bc  = 16;
constexpr int Nc  = 96;
constexpr int KRc = 16;
constexpr int KAc = 8;
constexpr int NOUT = KRc + KAc;        // 24
constexpr int NNb  = Nc - 1;           // 95 neighbors per atom
constexpr int PADN = 144;              // padded pair-shifted arrays (95+49)
constexpr float RCRf = 5.2f;
constexpr float RCAf = 3.5f;
constexpr float L2E  = 1.4426950408889634f;
}

typedef float v2f __attribute__((ext_vector_type(2)));
typedef float v4f __attribute__((ext_vector_type(4)));

__device__ __forceinline__ v2f sp(float x) { return (v2f){x, x}; }
__device__ __forceinline__ v2f pfma(v2f a, v2f b, v2f c) {
    return __builtin_elementwise_fma(a, b, c);
}
__device__ __forceinline__ v2f pmax(v2f a, v2f b) {
    return __builtin_elementwise_max(a, b);
}
__device__ __forceinline__ v2f pexp2(v2f x) {
    return (v2f){__builtin_amdgcn_exp2f(x.x), __builtin_amdgcn_exp2f(x.y)};
}
__device__ __forceinline__ v2f pcosr(v2f rev) {   // cos(2*pi*rev), rev >= 0
    return (v2f){__builtin_amdgcn_cosf(__builtin_amdgcn_fractf(rev.x)),
                 __builtin_amdgcn_cosf(__builtin_amdgcn_fractf(rev.y))};
}
__device__ __forceinline__ v2f psqrt(v2f x) {
    return (v2f){__builtin_amdgcn_sqrtf(x.x), __builtin_amdgcn_sqrtf(x.y)};
}
__device__ __forceinline__ float cos_rev(float rev) {
    return __builtin_amdgcn_cosf(__builtin_amdgcn_fractf(rev));
}

// R8 structure + 2-deep software-pipelined LDS prefetch + hoisted constants.
// 256 thr/block, grid 1536 (6 blocks/CU). Angular: t<190 active, j = t%95
// (A operand in registers), g = t/95 (g=0: rr 1..24, g=1: rr 25..48 with
// rr==48 y-lane masked in the last packed iter). Padded B arrays: the
// 12-iteration walk j2b+2*it never wraps -> immediate-offset ds_reads.
__global__ __launch_bounds__(256, 6) void ani_feat_kernel(
    const float* __restrict__ coords,      // (B,N,3)
    const int*   __restrict__ atom_types,  // (N,)
    const float* __restrict__ EtaR,        // (T,KR)
    const float* __restrict__ ShfR,        // (T,KR)
    const float* __restrict__ Zeta,        // (T,KA)
    const float* __restrict__ EtaA,        // (T,KA)
    float* __restrict__ out)               // (B,N,24)
{
    const int bi = blockIdx.x;             // b*N + i
    const int b  = bi / Nc;
    const int i  = bi - b * Nc;
    const int t  = threadIdx.x;

    __shared__ float4 su[NNb];             // unit vec x,y,z + d
    __shared__ float  ufa[NNb], sfr[NNb];
    __shared__ v4f  pxy[PADN];             // {x[s],x[s1],y[s],y[s1]}
    __shared__ v4f  pzd[PADN];             // {z[s],z[s1],d[s],d[s1]}
    __shared__ v2f  pfa[PADN];             // {fa[s],fa[s1]}
    __shared__ float pr[16][KRc];
    __shared__ float red[4][KAc];

    const int ti = atom_types[i];

    // ---- phase 1: scalar per-neighbor staging ----
    if (t < NNb) {
        const float* cb = coords + (size_t)(b * Nc) * 3;
        int j = t + (t >= i);
        float dx = cb[i*3+0] - cb[j*3+0];
        float dy = cb[i*3+1] - cb[j*3+1];
        float dz = cb[i*3+2] - cb[j*3+2];
        float d2 = dx*dx + dy*dy + dz*dz;
        float d  = __builtin_amdgcn_sqrtf(d2);
        float inv = __builtin_amdgcn_rcpf(d);
        su[t]  = make_float4(dx*inv, dy*inv, dz*inv, d);
        ufa[t] = fmaf(cos_rev(d * (0.5f / RCAf)), 0.5f, 0.5f);
        sfr[t] = fmaf(cos_rev(d * (0.5f / RCRf)), 0.5f, 0.5f);
    }

    // ---- fast-path detection from scalar (uniform) loads only ----
    bool fast;
    float ea0, dLs, c10;
    {
        float z0 = Zeta[ti * KAc + 0];
        bool zu = true;
#pragma unroll
        for (int k = 1; k < KAc; ++k) zu = zu && (Zeta[ti * KAc + k] == z0);
        float e0v = EtaA[ti * KAc + 0] * L2E;
        float e1v = EtaA[ti * KAc + 1] * L2E;
        float dv  = e1v - e0v;
        bool ar = true;
#pragma unroll
        for (int k = 2; k < KAc; ++k) {
            float ev = EtaA[ti * KAc + k] * L2E;
            ar = ar && (fabsf(ev - (e0v + dv * (float)k)) <=
                        1e-5f * fabsf(ev) + 1e-7f);
        }
        fast = zu && ar && (z0 == 32.0f);
        ea0 = e0v; dLs = dv; c10 = 1.0f - z0;
    }

    __syncthreads();

    // ---- phase 2: pair-shifted packed SoA, padded (no wrap in walk) ----
    if (t < NNb) {
        int s1 = t + 1; if (s1 >= NNb) s1 = 0;
        float4 a = su[t], c = su[s1];
        pxy[t] = (v4f){a.x, c.x, a.y, c.y};
        pzd[t] = (v4f){a.z, c.z, a.w, c.w};
        pfa[t] = (v2f){ufa[t], ufa[s1]};
    }
    if (t < PADN - NNb) {                  // mirror slots 0..48 -> 95..143
        int s1 = t + 1;                    // t<=48 -> s1<=49, no wrap
        float4 a = su[t], c = su[s1];
        pxy[NNb + t] = (v4f){a.x, c.x, a.y, c.y};
        pzd[NNb + t] = (v4f){a.z, c.z, a.w, c.w};
        pfa[NNb + t] = (v2f){ufa[t], ufa[s1]};
    }

    // ---- radial G2 (all 256 threads: 16 groups x 16 k) ----
    {
        const int k = t & 15, g2 = t >> 4;
        float er  = EtaR[ti * KRc + k];
        float sr  = ShfR[ti * KRc + k];
        float erL = -er * L2E;
        float acc = 0.0f;
        for (int jj = g2; jj < NNb; jj += 16) {
            float dd = su[jj].w - sr;
            acc += __builtin_amdgcn_exp2f(erL * dd * dd) * sfr[jj];
        }
        pr[g2][k] = acc;
    }
    __syncthreads();

    // ---- angular G3 ----
    const bool act = (t < 2 * NNb);        // 190 active
    const int  g   = (t >= NNb) ? 1 : 0;
    const int  j   = act ? (t - g * NNb) : 0;
    const float4 A  = su[j];
    const float faj = act ? ufa[j] : 0.0f;
    const float d2A  = A.w * A.w;
    const float m2Aw = -2.0f * A.w;
    const int   j2b  = j + (g ? 25 : 1);   // base index into padded arrays

    float av[KAc];

    if (fast) {
        v2f acc2[KAc];
#pragma unroll
        for (int k = 0; k < KAc; ++k) acc2[k] = sp(0.0f);

        if (act) {
            // y-lane of the last packed iter is rr==48: dead when g==1
            const v2f lastsel = g ? (v2f){1.0f, 0.0f} : sp(1.0f);

            // 3 rotating prefetch buffers (named, compile-time indexed)
            v4f xy_a, xy_b, xy_c, zd_a, zd_b, zd_c;
            v2f fb_a, fb_b, fb_c;

#define PRE(IT, V)                                                          \
            xy_##V = pxy[j2b + 2 * (IT)];                                   \
            zd_##V = pzd[j2b + 2 * (IT)];                                   \
            fb_##V = pfa[j2b + 2 * (IT)];

#define CMP(V, MSK)                                                         \
            {                                                               \
                v2f Bx = xy_##V.xy, By = xy_##V.zw;                         \
                v2f Bz = zd_##V.xy, Bw = zd_##V.zw;                         \
                v2f cosv = pfma(sp(A.x), Bx, pfma(sp(A.y), By, sp(A.z)*Bz));\
                v2f sAB  = pfma(Bw, Bw, sp(d2A));                           \
                v2f d23sq = pmax(pfma(sp(m2Aw)*Bw, cosv, sAB), sp(0.0f));   \
                v2f f23 = pfma(pcosr(psqrt(d23sq) * sp(0.5f/RCAf)),         \
                               sp(0.5f), sp(0.5f));                         \
                v2f fprod = fb_##V * f23;                                   \
                v2f s  = sAB + d23sq;                                       \
                v2f tt = cosv + sp(1.0f);      /* no clamp: ^32 is even */  \
                v2f t2 = tt*tt, t4 = t2*t2, t8 = t4*t4, t16 = t8*t8;        \
                v2f F  = t16 * t16 * fprod;                                 \
                MSK                                                         \
                v2f e0 = pexp2(sp(-ea0) * s);                               \
                v2f q  = pexp2(sp(-dLs) * s);                               \
                v2f q2 = q * q;                                             \
                v2f e1 = e0*q,  e2 = e0*q2, e3 = e1*q2;                     \
                v2f e4 = e2*q2, e5 = e3*q2, e6 = e4*q2, e7 = e5*q2;         \
                acc2[0] = pfma(F, e0, acc2[0]);                             \
                acc2[1] = pfma(F, e1, acc2[1]);                             \
                acc2[2] = pfma(F, e2, acc2[2]);                             \
                acc2[3] = pfma(F, e3, acc2[3]);                             \
                acc2[4] = pfma(F, e4, acc2[4]);                             \
                acc2[5] = pfma(F, e5, acc2[5]);                             \
                acc2[6] = pfma(F, e6, acc2[6]);                             \
                acc2[7] = pfma(F, e7, acc2[7]);                             \
            }

            // 2-deep pipelined schedule: loads issued 2 iterations early
            PRE(0, a)  PRE(1, b)  PRE(2, c)
            CMP(a, )   PRE(3, a)
            CMP(b, )   PRE(4, b)
            CMP(c, )   PRE(5, c)
            CMP(a, )   PRE(6, a)
            CMP(b, )   PRE(7, b)
            CMP(c, )   PRE(8, c)
            CMP(a, )   PRE(9, a)
            CMP(b, )   PRE(10, b)
            CMP(c, )   PRE(11, c)
            CMP(a, )
            CMP(b, )
            CMP(c, F = F * lastsel;)
#undef PRE
#undef CMP
        }
        // hoisted per-thread constants: faj and 2^(1-zeta)
        const float fin = faj * __builtin_amdgcn_exp2f(c10);
#pragma unroll
        for (int k = 0; k < KAc; ++k)
            av[k] = (acc2[k].x + acc2[k].y) * fin;
    } else {
        // generic fallback: reload params here (keeps fast path lean)
        float zek[KAc], c1k[KAc], eaL[KAc];
#pragma unroll
        for (int k = 0; k < KAc; ++k) {
            float z = Zeta[ti * KAc + k];
            zek[k] = z;
            c1k[k] = 1.0f - z;
            eaL[k] = EtaA[ti * KAc + k] * L2E;
        }
        float accS[KAc];
#pragma unroll
        for (int k = 0; k < KAc; ++k) accS[k] = 0.0f;

        if (act) {
            for (int r = 0; r < 24; ++r) {
                int rr = (g ? 25 : 1) + r;
                float lv = (rr <= 47) ? 1.0f : 0.0f;
                int j2 = j + rr; if (j2 >= NNb) j2 -= NNb;
                float4 Bq = su[j2];
                float fb = ufa[j2];
                float cosv = fmaf(A.x, Bq.x, fmaf(A.y, Bq.y, A.z * Bq.z));
                float sAB  = fmaf(Bq.w, Bq.w, d2A);
                float d23sq = fmaxf(fmaf(m2Aw * Bq.w, cosv, sAB), 0.0f);
                float d23 = __builtin_amdgcn_sqrtf(d23sq);
                float f23 = fmaf(cos_rev(d23 * (0.5f / RCAf)), 0.5f, 0.5f);
                float fprod = faj * fb * f23 * lv;
                float s  = sAB + d23sq;
                float tt = fmaxf(1.0f + cosv, 0.0f);
                float l2 = __builtin_amdgcn_logf(tt);   // log2; -inf at 0 ok
#pragma unroll
                for (int k = 0; k < KAc; ++k) {
                    float E = fmaf(zek[k], l2, c1k[k]);
                    E = fmaf(-eaL[k], s, E);
                    accS[k] += __builtin_amdgcn_exp2f(E) * fprod;
                }
            }
        }
#pragma unroll
        for (int k = 0; k < KAc; ++k) av[k] = accS[k];
    }

    // ---- reductions ----
    const int lane = t & 63, wv = t >> 6;
#pragma unroll
    for (int k = 0; k < KAc; ++k) {
        float v = av[k];
#pragma unroll
        for (int off = 32; off; off >>= 1) v += __shfl_xor(v, off, 64);
        if (lane == 0) red[wv][k] = v;
    }
    __syncthreads();

    if (t < KAc) {
        out[bi * NOUT + KRc + t] =
            red[0][t] + red[1][t] + red[2][t] + red[3][t];
    }
    if (t < KRc) {
        float s = 0.0f;
#pragma unroll
        for (int g2 = 0; g2 < 16; ++g2) s += pr[g2][t];
        out[bi * NOUT + t] = s;
    }
}

extern "C" void kernel_launch(void* const* d_in, const int* in_sizes, int n_in,
                              void* d_out, int out_size, void* d_ws, size_t ws_size,
                              hipStream_t stream) {
    const float* coords     = (const float*)d_in[0];
    const int*   atom_types = (const int*)d_in[1];
    const float* EtaR       = (const float*)d_in[2];
    const float* ShfR       = (const float*)d_in[3];
    const float* Zeta       = (const float*)d_in[4];
    const float* EtaA       = (const float*)d_in[5];
    float* out = (float*)d_out;

    ani_feat_kernel<<<dim3(Bc * Nc), dim3(256), 0, stream>>>(
        coords, atom_types, EtaR, ShfR, Zeta, EtaA, out);
}

// Round 13
// 15.875 us; speedup vs baseline: 11.2971x; 1.0584x over previous
//
#include <hip/hip_runtime.h>

namespace {
constexpr int Bc  = 16;
constexpr int Nc  = 96;
constexpr int KRc = 16;
constexpr int KAc = 8;
constexpr int NOUT = KRc + KAc;        // 24
constexpr int NNb  = Nc - 1;           // 95 neighbors per atom
constexpr float RCRf = 5.2f;
constexpr float RCAf = 3.5f;
constexpr float L2E  = 1.4426950408889634f;
}

__device__ __forceinline__ float cos_rev(float rev) {   // cos(2*pi*rev)
    return __builtin_amdgcn_cosf(__builtin_amdgcn_fractf(rev));
}
__device__ __forceinline__ float exp2g(float x) {
    return __builtin_amdgcn_exp2f(x);
}

// Distance-culled ANI features.
// Drop bound (angular): term <= 2*2^(-eamin*s), s >= d2a+d2b; keeping only
// neighbors with d2 <= THR = 26/eamin drops < 4465*2*2^-26 ~ 1.4e-4 total
// (threshold 0.11). Radial gated by er*(sqrt(THR)-sr)^2 >= 16 for all k.
// Compaction is ballot-based (deterministic), M is block-uniform.
__global__ __launch_bounds__(256, 6) void ani_feat_kernel(
    const float* __restrict__ coords,      // (B,N,3)
    const int*   __restrict__ atom_types,  // (N,)
    const float* __restrict__ EtaR,        // (T,KR)
    const float* __restrict__ ShfR,        // (T,KR)
    const float* __restrict__ Zeta,        // (T,KA)
    const float* __restrict__ EtaA,        // (T,KA)
    float* __restrict__ out)               // (B,N,24)
{
    const int bi = blockIdx.x;             // b*N + i
    const int b  = bi / Nc;
    const int i  = bi - b * Nc;
    const int t  = threadIdx.x;
    const int lane = t & 63, wv = t >> 6;

    __shared__ float4 su[NNb];             // original: unit vec + d
    __shared__ float  ufa[NNb], sfr[NNb];  // original cutoffs
    __shared__ float4 ca4[NNb];            // compacted: unit vec + d
    __shared__ float  cfa[NNb], cfr[NNb];  // compacted cutoffs
    __shared__ float  pr[16][KRc];
    __shared__ float  red[4][KAc];
    __shared__ int    sM[2];

    const int ti = atom_types[i];

    // ---- fast-path detection + thresholds (uniform scalar loads) ----
    bool fast;
    float ea0, dLs, c10, THR;
    {
        float z0 = Zeta[ti * KAc + 0];
        bool zu = true;
#pragma unroll
        for (int k = 1; k < KAc; ++k) zu = zu && (Zeta[ti * KAc + k] == z0);
        ea0 = EtaA[ti * KAc + 0] * L2E;
        float e1v = EtaA[ti * KAc + 1] * L2E;
        dLs = e1v - ea0;
        bool ar = true;
#pragma unroll
        for (int k = 2; k < KAc; ++k) {
            float ev = EtaA[ti * KAc + k] * L2E;
            ar = ar && (fabsf(ev - (ea0 + dLs * (float)k)) <=
                        1e-5f * fabsf(ev) + 1e-7f);
        }
        float eamin = fminf(ea0, ea0 + 7.0f * dLs);
        fast = zu && ar && (z0 == 32.0f) && (eamin > 1e-6f);
        THR  = fast ? (26.0f / eamin) : 1e30f;   // d2 cull threshold
        c10  = 1.0f - z0;
    }

    // ---- staging (t<95) + wave0 compaction ----
    float st_ux = 0, st_uy = 0, st_uz = 0, st_d = 0, st_fa = 0, st_fr = 0;
    bool pred = false;
    if (t < NNb) {
        const float* cb = coords + (size_t)(b * Nc) * 3;
        int j = t + (t >= i);
        float dx = cb[i*3+0] - cb[j*3+0];
        float dy = cb[i*3+1] - cb[j*3+1];
        float dz = cb[i*3+2] - cb[j*3+2];
        float d2 = dx*dx + dy*dy + dz*dz;
        float d  = __builtin_amdgcn_sqrtf(d2);
        float inv = __builtin_amdgcn_rcpf(d);
        st_ux = dx*inv; st_uy = dy*inv; st_uz = dz*inv; st_d = d;
        st_fa = fmaf(cos_rev(d * (0.5f / RCAf)), 0.5f, 0.5f);
        st_fr = fmaf(cos_rev(d * (0.5f / RCRf)), 0.5f, 0.5f);
        su[t]  = make_float4(st_ux, st_uy, st_uz, d);
        ufa[t] = st_fa;
        sfr[t] = st_fr;
        pred = (d2 <= THR);
    }
    unsigned long long mask = __ballot(pred);
    unsigned long long ltm  = (1ull << lane) - 1ull;
    if (wv == 0) {
        int pos = (int)__popcll(mask & ltm);
        if (pred) {
            ca4[pos] = make_float4(st_ux, st_uy, st_uz, st_d);
            cfa[pos] = st_fa; cfr[pos] = st_fr;
        }
        if (t == 0) sM[0] = (int)__popcll(mask);
    }
    __syncthreads();                       // B1

    if (wv == 1) {
        int base = sM[0];
        int pos = base + (int)__popcll(mask & ltm);
        if (pred) {
            ca4[pos] = make_float4(st_ux, st_uy, st_uz, st_d);
            cfa[pos] = st_fa; cfr[pos] = st_fr;
        }
        if (lane == 0) sM[1] = base + (int)__popcll(mask);
    }
    __syncthreads();                       // B2

    const int M = sM[1];

    // ---- radial G2: compacted if the per-k bound holds, else full ----
    {
        const int k = t & 15, g2 = t >> 4;
        float er  = EtaR[ti * KRc + k];
        float sr  = ShfR[ti * KRc + k];
        float sqT = __builtin_amdgcn_sqrtf(THR);
        bool okk = (sr < sqT) && (er * (sqT - sr) * (sqT - sr) >= 16.0f);
        bool okr = __all(okk) && fast;
        float erL = -er * L2E;
        float acc = 0.0f;
        if (okr) {
            for (int jj = g2; jj < M; jj += 16) {
                float dd = ca4[jj].w - sr;
                acc += exp2g(erL * dd * dd) * cfr[jj];
            }
        } else {
            for (int jj = g2; jj < NNb; jj += 16) {
                float dd = su[jj].w - sr;
                acc += exp2g(erL * dd * dd) * sfr[jj];
            }
        }
        pr[g2][k] = acc;
    }

    // ---- angular G3 ----
    float av[KAc];

    if (fast) {
        float acc[KAc];
#pragma unroll
        for (int k = 0; k < KAc; ++k) acc[k] = 0.0f;

        // round-robin pair cover over M compacted items:
        // rr=1..K full rows (a=0..M-1), plus half row rr=M/2 when M even
        const int K      = (M - 1) >> 1;
        const int fullS  = M * K;
        const int tailS  = (M & 1) ? 0 : (M >> 1);
        const int nps    = fullS + tailS;
        const int rounds = (nps + 255) >> 8;
        const float invM = 1.0f / (float)M;

        for (int r = 0; r < rounds; ++r) {
            int slot = (r << 8) + t;
            bool valid = slot < nps;
            int a, rr;
            if (slot < fullS) {
                int rp = (int)((float)slot * invM);
                a = slot - rp * M;
                if (a < 0)       { --rp; a += M; }
                else if (a >= M) { ++rp; a -= M; }
                rr = rp + 1;
            } else {
                a  = slot - fullS;
                rr = M >> 1;
            }
            if (!valid) { a = 0; rr = 0; }
            int bq = a + rr; if (bq >= M) bq -= M;

            float4 A  = ca4[a];
            float4 Bv = ca4[bq];
            float faa = cfa[a], fab = cfa[bq];
            float da = A.w, db = Bv.w;
            float cosv = fmaf(A.x, Bv.x, fmaf(A.y, Bv.y, A.z * Bv.z));
            float sAB  = fmaf(da, da, db * db);
            float d23sq = fmaxf(fmaf(-2.0f * da * db, cosv, sAB), 0.0f);
            float f23 = fmaf(cos_rev(__builtin_amdgcn_sqrtf(d23sq) *
                                     (0.5f / RCAf)), 0.5f, 0.5f);
            float fprod = faa * fab * f23;
            float s  = sAB + d23sq;
            float tt = 1.0f + cosv;              // ^32 is even: no clamp
            float t2 = tt*tt, t4 = t2*t2, t8 = t4*t4, t16 = t8*t8;
            float F  = t16 * t16 * fprod;
            F = valid ? F : 0.0f;
            float e0 = exp2g(-ea0 * s);
            float q  = exp2g(-dLs * s);
            float q2 = q * q;
            float e1 = e0*q,  e2 = e0*q2, e3 = e1*q2;
            float e4 = e2*q2, e5 = e3*q2, e6 = e4*q2, e7 = e5*q2;
            acc[0] = fmaf(F, e0, acc[0]);
            acc[1] = fmaf(F, e1, acc[1]);
            acc[2] = fmaf(F, e2, acc[2]);
            acc[3] = fmaf(F, e3, acc[3]);
            acc[4] = fmaf(F, e4, acc[4]);
            acc[5] = fmaf(F, e5, acc[5]);
            acc[6] = fmaf(F, e6, acc[6]);
            acc[7] = fmaf(F, e7, acc[7]);
        }
        const float p21z = exp2g(c10);           // 2^(1-zeta), hoisted
#pragma unroll
        for (int k = 0; k < KAc; ++k) av[k] = acc[k] * p21z;
    } else {
        // generic fallback (R8 structure): 190 threads, full 95 neighbors
        float zek[KAc], c1k[KAc], eaL[KAc];
#pragma unroll
        for (int k = 0; k < KAc; ++k) {
            float z = Zeta[ti * KAc + k];
            zek[k] = z;
            c1k[k] = 1.0f - z;
            eaL[k] = EtaA[ti * KAc + k] * L2E;
        }
        float accS[KAc];
#pragma unroll
        for (int k = 0; k < KAc; ++k) accS[k] = 0.0f;

        const bool act = (t < 2 * NNb);
        const int  g   = (t >= NNb) ? 1 : 0;
        const int  j   = act ? (t - g * NNb) : 0;
        if (act) {
            float4 A = su[j];
            float faj = ufa[j];
            float d2A = A.w * A.w;
            float m2Aw = -2.0f * A.w;
            for (int r = 0; r < 24; ++r) {
                int rr = (g ? 25 : 1) + r;
                float lv = (rr <= 47) ? 1.0f : 0.0f;
                int j2 = j + rr; if (j2 >= NNb) j2 -= NNb;
                float4 Bq = su[j2];
                float fb = ufa[j2];
                float cosv = fmaf(A.x, Bq.x, fmaf(A.y, Bq.y, A.z * Bq.z));
                float sAB  = fmaf(Bq.w, Bq.w, d2A);
                float d23sq = fmaxf(fmaf(m2Aw * Bq.w, cosv, sAB), 0.0f);
                float d23 = __builtin_amdgcn_sqrtf(d23sq);
                float f23 = fmaf(cos_rev(d23 * (0.5f / RCAf)), 0.5f, 0.5f);
                float fprod = faj * fb * f23 * lv;
                float s  = sAB + d23sq;
                float tt = fmaxf(1.0f + cosv, 0.0f);
                float l2 = __builtin_amdgcn_logf(tt);   // log2; -inf at 0 ok
#pragma unroll
                for (int k = 0; k < KAc; ++k) {
                    float E = fmaf(zek[k], l2, c1k[k]);
                    E = fmaf(-eaL[k], s, E);
                    accS[k] += exp2g(E) * fprod;
                }
            }
        }
#pragma unroll
        for (int k = 0; k < KAc; ++k) av[k] = accS[k];
    }

    // ---- reductions ----
#pragma unroll
    for (int k = 0; k < KAc; ++k) {
        float v = av[k];
#pragma unroll
        for (int off = 32; off; off >>= 1) v += __shfl_xor(v, off, 64);
        if (lane == 0) red[wv][k] = v;
    }
    __syncthreads();                       // B3

    if (t < KAc) {
        out[bi * NOUT + KRc + t] =
            red[0][t] + red[1][t] + red[2][t] + red[3][t];
    }
    if (t < KRc) {
        float s = 0.0f;
#pragma unroll
        for (int g2 = 0; g2 < 16; ++g2) s += pr[g2][t];
        out[bi * NOUT + t] = s;
    }
}

extern "C" void kernel_launch(void* const* d_in, const int* in_sizes, int n_in,
                              void* d_out, int out_size, void* d_ws, size_t ws_size,
                              hipStream_t stream) {
    const float* coords     = (const float*)d_in[0];
    const int*   atom_types = (const int*)d_in[1];
    const float* EtaR       = (const float*)d_in[2];
    const float* ShfR       = (const float*)d_in[3];
    const float* Zeta       = (const float*)d_in[4];
    const float* EtaA       = (const float*)d_in[5];
    float* out = (float*)d_out;

    ani_feat_kernel<<<dim3(Bc * Nc), dim3(256), 0, stream>>>(
        coords, atom_types, EtaR, ShfR, Zeta, EtaA, out);
}